// Round 12
// baseline (224.904 us; speedup 1.0000x reference)
//
#include <hip/hip_runtime.h>
#include <hip/hip_bf16.h>

#define N_B 8
#define CH 256
#define HW 2304           // 48*48
#define SZ_QS (2304LL*2304LL)
#define SCALE 0.0390625f  // 10/256
#define EPSC 0.999999f

typedef __attribute__((ext_vector_type(8))) short bf8_t;
typedef __attribute__((ext_vector_type(8))) unsigned short u16x8;
typedef __attribute__((ext_vector_type(4))) float f32x4;

// output offsets in floats
#define O1 0LL
#define O2 42467328LL
#define O3 84934656LL
#define O4 87588864LL
#define O5 90243072LL
#define O6 132710400LL

// async global->LDS, 16B per lane, linear LDS dest (wave-uniform base + lane*16)
__device__ __forceinline__ void gl_lds16(const unsigned short* g, unsigned short* l) {
  __builtin_amdgcn_global_load_lds(
      (const __attribute__((address_space(1))) unsigned int*)g,
      (__attribute__((address_space(3))) unsigned int*)l, 16, 0, 0);
}

// ---------------------------------------------------------------------------
// Shared GEMM core: 192x192 tile, 512 thr (2x4 waves), K=256, BK=32
// double-buffered 2-phase pipeline (R11-proven).  smem = 48 KB staging.
// Produces exact f32 acc[6][3] in the standard C/D fragment layout.
// ---------------------------------------------------------------------------
__device__ __forceinline__ void gemm192(
    const unsigned short* __restrict__ Abf, const unsigned short* __restrict__ Bbf,
    unsigned short* __restrict__ smem, const int n, const int S0, const int Q0,
    const int t, f32x4 (&acc)[6][3]) {
  const int l = t & 63, w = t >> 6;
  const int wm = w >> 1 >> 1, wn = w & 3;  // wm = w>>2
  const int g = l >> 4, c = l & 15;

#pragma unroll
  for (int mi = 0; mi < 6; ++mi)
#pragma unroll
    for (int ni = 0; ni < 3; ++ni) {
      f32x4 z = {0.f, 0.f, 0.f, 0.f};
      acc[mi][ni] = z;
    }

  // staging: 24 chunks of 16 rows (12 A + 12 B), 3 per wave; source-swizzled.
  const int rrel = l >> 2;
  const int sseg = (l & 3) ^ ((l >> 3) & 3);
  const unsigned short* gAb = Abf + ((size_t)n * HW + Q0) * CH;
  const unsigned short* gBb = Bbf + ((size_t)n * HW + S0) * CH;
  const int ch0 = w * 3;

#define STAGE_CHUNK(chv, buf, k0)                                              \
  {                                                                            \
    const int isA = (chv) < 12;                                                \
    const int crel = isA ? (chv) : (chv)-12;                                   \
    const unsigned short* sp_ =                                                \
        (isA ? gAb : gBb) + (size_t)(crel * 16 + rrel) * CH + (k0) + sseg * 8; \
    unsigned short* dp_ = smem + (buf)*12288 + (isA ? 0 : 6144) + crel * 512;  \
    gl_lds16(sp_, dp_);                                                        \
  }

  STAGE_CHUNK(ch0 + 0, 0, 0);
  STAGE_CHUNK(ch0 + 1, 0, 0);
  STAGE_CHUNK(ch0 + 2, 0, 0);
  __syncthreads();

  int cur = 0;
#pragma unroll 2
  for (int step = 0; step < 8; ++step) {
    if (step < 7) {
      const int k0_ = (step + 1) * 32;
      STAGE_CHUNK(ch0 + 0, cur ^ 1, k0_);
      STAGE_CHUNK(ch0 + 1, cur ^ 1, k0_);
      STAGE_CHUNK(ch0 + 2, cur ^ 1, k0_);
    }
    const unsigned short* lA = smem + cur * 12288;
    const unsigned short* lB = lA + 6144;
    bf8_t af[6], bf_[3];
    const int sg_ = g ^ ((c >> 1) & 3);
#pragma unroll
    for (int mi = 0; mi < 6; ++mi) {
      const int r = wm * 96 + mi * 16 + c;
      af[mi] = *(const bf8_t*)(lA + r * 32 + sg_ * 8);
    }
#pragma unroll
    for (int ni = 0; ni < 3; ++ni) {
      const int r = wn * 48 + ni * 16 + c;
      bf_[ni] = *(const bf8_t*)(lB + r * 32 + sg_ * 8);
    }
#pragma unroll
    for (int mi = 0; mi < 6; ++mi)
#pragma unroll
      for (int ni = 0; ni < 3; ++ni)
        acc[mi][ni] = __builtin_amdgcn_mfma_f32_16x16x32_bf16(af[mi], bf_[ni], acc[mi][ni], 0, 0, 0);
    __syncthreads();  // drains stage loads + protects buffer swap
    cur ^= 1;
  }
#undef STAGE_CHUNK

  // e = exp(SCALE*acc)
#pragma unroll
  for (int mi = 0; mi < 6; ++mi)
#pragma unroll
    for (int ni = 0; ni < 3; ++ni)
#pragma unroll
      for (int r = 0; r < 4; ++r)
        acc[mi][ni][r] = __expf(acc[mi][ni][r] * SCALE);
}

// ---------------------------------------------------------------------------
// K0: transpose+convert fp32 [n][c][hw] -> bf16 [n][hw][c], wide 16B stores.
// Side job: 36 blocks (y==0, z==0) zero the sum buffers (if zbuf != null).
// ---------------------------------------------------------------------------
__global__ __launch_bounds__(256) void k_tr(const float* __restrict__ q_in,
                                            const float* __restrict__ m_in,
                                            __hip_bfloat16* __restrict__ Abf,
                                            __hip_bfloat16* __restrict__ Bbf,
                                            float* __restrict__ zbuf) {
  __shared__ float lds[64][65];
  const int n = blockIdx.z >> 1, which = blockIdx.z & 1;
  const float* src = which ? m_in : q_in;
  __hip_bfloat16* dst = which ? Bbf : Abf;
  const int q0 = blockIdx.x * 64, c0 = blockIdx.y * 64;
  const int t = threadIdx.x;

  if (zbuf && blockIdx.y == 0 && blockIdx.z == 0) {
    const int i = (blockIdx.x * 256 + t) * 4;  // 36*256*4 = 36864 = 2*N_B*HW
    *(float4*)(zbuf + i) = make_float4(0.f, 0.f, 0.f, 0.f);
  }

  const int cl4 = t >> 4, q4 = (t & 15) * 4;
#pragma unroll
  for (int p = 0; p < 4; ++p) {
    const int cl = p * 16 + cl4;
    const float4 v = *(const float4*)(src + ((size_t)n * CH + c0 + cl) * HW + q0 + q4);
    lds[cl][q4 + 0] = v.x;
    lds[cl][q4 + 1] = v.y;
    lds[cl][q4 + 2] = v.z;
    lds[cl][q4 + 3] = v.w;
  }
  __syncthreads();

  const int c8 = (t & 7) * 8;
#pragma unroll
  for (int p = 0; p < 2; ++p) {
    const int ql = p * 32 + (t >> 3);
    u16x8 o;
#pragma unroll
    for (int k = 0; k < 8; ++k) {
      const __hip_bfloat16 h = __float2bfloat16(lds[c8 + k][ql]);
      o[k] = *(const unsigned short*)&h;
    }
    *(u16x8*)((unsigned short*)dst + ((size_t)n * HW + q0 + ql) * CH + c0 + c8) = o;
  }
}

__global__ __launch_bounds__(256) void k_zero(float* __restrict__ p) {
  const int i = (blockIdx.x * 256 + threadIdx.x) * 4;
  *(float4*)(p + i) = make_float4(0.f, 0.f, 0.f, 0.f);
}

__global__ __launch_bounds__(256) void k_inv(const float* __restrict__ s,
                                             float* __restrict__ inv,
                                             const float scale) {
  const int i = blockIdx.x * 256 + threadIdx.x;
  inv[i] = scale / s[i];
}

// ---------------------------------------------------------------------------
// Pass 1: pipelined GEMM + row/col sum atomics ONLY (no e materialization).
// ---------------------------------------------------------------------------
__global__ __launch_bounds__(512) void k_p1(
    const unsigned short* __restrict__ Abf, const unsigned short* __restrict__ Bbf,
    float* __restrict__ rowsum, float* __restrict__ colsum) {
  __shared__ char smem[49152];
  const int n = blockIdx.z;
  const int S0 = blockIdx.x * 192, Q0 = blockIdx.y * 192;
  const int t = threadIdx.x, l = t & 63, w = t >> 6;
  const int wm = w >> 2, wn = w & 3;
  const int g = l >> 4, c = l & 15;

  f32x4 acc[6][3];
  gemm192(Abf, Bbf, (unsigned short*)smem, n, S0, Q0, t, acc);

#pragma unroll
  for (int mi = 0; mi < 6; ++mi)
#pragma unroll
    for (int r = 0; r < 4; ++r) {
      float v = acc[mi][0][r] + acc[mi][1][r] + acc[mi][2][r];
      v += __shfl_xor(v, 1, 64);
      v += __shfl_xor(v, 2, 64);
      v += __shfl_xor(v, 4, 64);
      v += __shfl_xor(v, 8, 64);
      if (c == 0) atomicAdd(&rowsum[n * HW + Q0 + wm * 96 + mi * 16 + g * 4 + r], v);
    }
#pragma unroll
  for (int ni = 0; ni < 3; ++ni) {
    float v = 0.f;
#pragma unroll
    for (int mi = 0; mi < 6; ++mi)
#pragma unroll
      for (int r = 0; r < 4; ++r) v += acc[mi][ni][r];
    v += __shfl_xor(v, 16, 64);
    v += __shfl_xor(v, 32, 64);
    if (g == 0) atomicAdd(&colsum[n * HW + S0 + wn * 48 + ni * 16 + c], v);
  }
}

// ---------------------------------------------------------------------------
// Pass 2: recompute e via the same pipelined GEMM (exact f32 — no quant),
// inverses inline, then the proven epilogue phases A-D.
// LDS unioned: 48 KB staging during GEMM, then reused as fb (37.6 KB).
// ---------------------------------------------------------------------------
__global__ __launch_bounds__(512) void k_p2(
    const unsigned short* __restrict__ Abf, const unsigned short* __restrict__ Bbf,
    float* __restrict__ out1, float* __restrict__ out2, float* __restrict__ out3,
    float* __restrict__ out4, float* __restrict__ out5, float* __restrict__ out6,
    const float* __restrict__ rowsum, const float* __restrict__ colsum) {
  __shared__ char smem[49152];
  const int n = blockIdx.z;
  const int bx = blockIdx.x, hq = blockIdx.y;
  const int S0 = bx * 192, Q0 = hq * 192;
  const int t = threadIdx.x, l = t & 63, w = t >> 6;
  const int wm = w >> 2, wn = w & 3;
  const int g = l >> 4, c = l & 15;

  f32x4 acc[6][3];
  gemm192(Abf, Bbf, (unsigned short*)smem, n, S0, Q0, t, acc);
  // last gemm barrier guarantees all LDS reads done -> safe to reuse as fb
  float* fb = (float*)smem;  // 48 x 196 floats

  // inverses (exact f32 sums; no dequant factor)
  float icv[3];
#pragma unroll
  for (int ni = 0; ni < 3; ++ni)
    icv[ni] = 1.0f / colsum[n * HW + S0 + wn * 48 + ni * 16 + c];
  f32x4 irv6[6];
#pragma unroll
  for (int mi = 0; mi < 6; ++mi) {
    const int qloc = wm * 96 + mi * 16 + g * 4;
    const f32x4 rs = *(const f32x4*)(rowsum + n * HW + Q0 + qloc);
#pragma unroll
    for (int r = 0; r < 4; ++r) irv6[mi][r] = 1.0f / rs[r];
  }

  // Phase A: pi tile (out1 rows q, out5 remapped), 4 chunks of 48 q-rows
#pragma unroll
  for (int ch = 0; ch < 4; ++ch) {
    if (wm == (ch >> 1)) {
#pragma unroll
      for (int m3 = 0; m3 < 3; ++m3) {
        const int mi = (ch & 1) * 3 + m3;
        const int rowb = m3 * 16 + g * 4;
#pragma unroll
        for (int ni = 0; ni < 3; ++ni) {
          const int colb = wn * 48 + ni * 16 + c;
#pragma unroll
          for (int r = 0; r < 4; ++r)
            fb[(rowb + r) * 196 + colb] = acc[mi][ni][r] * icv[ni];
        }
      }
    }
    __syncthreads();
#pragma unroll
    for (int j = 0; j < 5; ++j) {
      const int idx = t + j * 512;
      if (idx < 2304) {
        const int row = idx / 48, col4 = idx % 48;
        const float4 v = *(const float4*)(fb + row * 196 + col4 * 4);
        *(float4*)(out1 + ((size_t)n * HW + Q0 + ch * 48 + row) * HW + S0 + col4 * 4) = v;
        const size_t r5 = ((size_t)n * 144 + hq * 12 + (row >> 2)) * 16 + ch * 4 + (row & 3);
        *(float4*)(out5 + r5 * HW + S0 + col4 * 4) = v;
      }
    }
    __syncthreads();
  }

  // Phase B: pq tile (out2 rows s, out6 remapped), 4 chunks of 48 s-rows (= wn)
#pragma unroll
  for (int ch = 0; ch < 4; ++ch) {
    if (wn == ch) {
#pragma unroll
      for (int mi = 0; mi < 6; ++mi) {
        const int colf = wm * 96 + mi * 16 + g * 4;
#pragma unroll
        for (int ni = 0; ni < 3; ++ni) {
          const f32x4 pq = acc[mi][ni] * irv6[mi];
          *(f32x4*)(fb + (ni * 16 + c) * 196 + colf) = pq;
        }
      }
    }
    __syncthreads();
#pragma unroll
    for (int j = 0; j < 5; ++j) {
      const int idx = t + j * 512;
      if (idx < 2304) {
        const int row = idx / 48, col4 = idx % 48;
        const float4 v = *(const float4*)(fb + row * 196 + col4 * 4);
        *(float4*)(out2 + ((size_t)n * HW + S0 + ch * 48 + row) * HW + Q0 + col4 * 4) = v;
        const size_t r6 = ((size_t)n * 144 + bx * 12 + (row >> 2)) * 16 + ch * 4 + (row & 3);
        *(float4*)(out6 + r6 * HW + Q0 + col4 * 4) = v;
      }
    }
    __syncthreads();
  }

  // Phase C: out3 (instance_d) — per-thread patch partials, combine wm halves
#pragma unroll
  for (int m3 = 0; m3 < 3; ++m3) {
    const int b = m3 * 4 + g;  // q-patch col 0..11
#pragma unroll
    for (int ni = 0; ni < 3; ++ni) {
      const int sl = wn * 48 + ni * 16 + c;
      float p = 0.f;
#pragma unroll
      for (int r = 0; r < 4; ++r) p += acc[m3][ni][r] + acc[m3 + 3][ni][r];
      fb[(wm * 12 + b) * 196 + sl] = p * icv[ni];
    }
  }
  __syncthreads();
#pragma unroll
  for (int j = 0; j < 5; ++j) {
    const int idx = t + j * 512;
    if (idx < 2304) {
      const int b = idx / 192, sl = idx % 192;
      const float v = fb[b * 196 + sl] + fb[(12 + b) * 196 + sl];
      out3[((size_t)n * 144 + hq * 12 + b) * HW + S0 + sl] = fminf(v, EPSC);
    }
  }
  __syncthreads();

  // Phase D: out4 (query_d) — 4-lane shfl, combine 4 wn waves in LDS
#pragma unroll
  for (int mi = 0; mi < 6; ++mi) {
    const int qloc = wm * 96 + mi * 16 + g * 4;
#pragma unroll
    for (int ni = 0; ni < 3; ++ni) {
      f32x4 pq = acc[mi][ni] * irv6[mi];
#pragma unroll
      for (int r = 0; r < 4; ++r) {
        pq[r] += __shfl_xor(pq[r], 1, 64);
        pq[r] += __shfl_xor(pq[r], 2, 64);
      }
      if ((c & 3) == 0) {
        const int pc = ni * 4 + (c >> 2);  // s-patch col 0..11
        *(f32x4*)(fb + (wn * 12 + pc) * 196 + qloc) = pq;
      }
    }
  }
  __syncthreads();
#pragma unroll
  for (int j = 0; j < 5; ++j) {
    const int idx = t + j * 512;
    if (idx < 2304) {
      const int pc = idx / 192, q = idx % 192;
      const float v = fb[pc * 196 + q] + fb[(12 + pc) * 196 + q] +
                      fb[(24 + pc) * 196 + q] + fb[(36 + pc) * 196 + q];
      out4[((size_t)n * 144 + bx * 12 + pc) * HW + Q0 + q] = fminf(v, EPSC);
    }
  }
}

// ===========================================================================
// Fallback path (ws too small): old validated kernels
// ===========================================================================
__global__ __launch_bounds__(256) void k_gemm_old(const unsigned short* __restrict__ Abf,
                                                  const unsigned short* __restrict__ Bbf,
                                                  float* __restrict__ out1,
                                                  float* __restrict__ rowsum,
                                                  float* __restrict__ colsum) {
  __shared__ unsigned short lA[128 * 64];
  __shared__ unsigned short lB[128 * 64];
  const int n = blockIdx.z;
  const int s0 = blockIdx.x * 128, q0 = blockIdx.y * 128;
  const int t = threadIdx.x, l = t & 63, w = t >> 6;
  const int wm = w >> 1, wn = w & 1;
  f32x4 acc[4][4];
#pragma unroll
  for (int mi = 0; mi < 4; ++mi)
#pragma unroll
    for (int ni = 0; ni < 4; ++ni) {
      f32x4 z = {0.f, 0.f, 0.f, 0.f};
      acc[mi][ni] = z;
    }
  const size_t baseA = ((size_t)n * HW + q0) * CH;
  const size_t baseB = ((size_t)n * HW + s0) * CH;
  const int jj = t & 7, rr = t >> 3;
  for (int kc = 0; kc < 4; ++kc) {
    const int k0 = kc * 64;
#pragma unroll
    for (int i = 0; i < 4; ++i) {
      const int r = i * 32 + rr;
      bf8_t va = *(const bf8_t*)(Abf + baseA + (size_t)r * CH + k0 + jj * 8);
      bf8_t vb = *(const bf8_t*)(Bbf + baseB + (size_t)r * CH + k0 + jj * 8);
      *(bf8_t*)(lA + r * 64 + ((jj ^ (r & 7)) * 8)) = va;
      *(bf8_t*)(lB + r * 64 + ((jj ^ (r & 7)) * 8)) = vb;
    }
    __syncthreads();
#pragma unroll
    for (int ks = 0; ks < 2; ++ks) {
      const int kb = ks * 4 + (l >> 4);
      bf8_t af[4], bfr[4];
#pragma unroll
      for (int mi = 0; mi < 4; ++mi) {
        const int r = wm * 64 + mi * 16 + (l & 15);
        af[mi] = *(const bf8_t*)(lA + r * 64 + ((kb ^ (r & 7)) * 8));
      }
#pragma unroll
      for (int ni = 0; ni < 4; ++ni) {
        const int r = wn * 64 + ni * 16 + (l & 15);
        bfr[ni] = *(const bf8_t*)(lB + r * 64 + ((kb ^ (r & 7)) * 8));
      }
#pragma unroll
      for (int mi = 0; mi < 4; ++mi)
#pragma unroll
        for (int ni = 0; ni < 4; ++ni)
          acc[mi][ni] = __builtin_amdgcn_mfma_f32_16x16x32_bf16(af[mi], bfr[ni], acc[mi][ni], 0, 0, 0);
    }
    __syncthreads();
  }
  float rp[4][4], cp[4];
#pragma unroll
  for (int mi = 0; mi < 4; ++mi)
#pragma unroll
    for (int r = 0; r < 4; ++r) rp[mi][r] = 0.f;
#pragma unroll
  for (int ni = 0; ni < 4; ++ni) cp[ni] = 0.f;
#pragma unroll
  for (int mi = 0; mi < 4; ++mi) {
    const int row = q0 + wm * 64 + mi * 16 + (l >> 4) * 4;
#pragma unroll
    for (int ni = 0; ni < 4; ++ni) {
      const int col = s0 + wn * 64 + ni * 16 + (l & 15);
      const size_t ob = ((size_t)n * HW + row) * HW + col;
#pragma unroll
      for (int r = 0; r < 4; ++r) {
        const float e = __expf(acc[mi][ni][r] * SCALE);
        out1[ob + (size_t)r * HW] = e;
        rp[mi][r] += e;
        cp[ni] += e;
      }
    }
  }
#pragma unroll
  for (int mi = 0; mi < 4; ++mi)
#pragma unroll
    for (int r = 0; r < 4; ++r) {
      float v = rp[mi][r];
      v += __shfl_xor(v, 1, 64);
      v += __shfl_xor(v, 2, 64);
      v += __shfl_xor(v, 4, 64);
      v += __shfl_xor(v, 8, 64);
      if ((l & 15) == 0)
        atomicAdd(&rowsum[n * HW + q0 + wm * 64 + mi * 16 + (l >> 4) * 4 + r], v);
    }
#pragma unroll
  for (int ni = 0; ni < 4; ++ni) {
    float v = cp[ni];
    v += __shfl_xor(v, 16, 64);
    v += __shfl_xor(v, 32, 64);
    if (l < 16) atomicAdd(&colsum[n * HW + s0 + wn * 64 + ni * 16 + l], v);
  }
}

__global__ __launch_bounds__(192) void k_main(float* __restrict__ out1,
                                              float* __restrict__ out2,
                                              float* __restrict__ out3,
                                              float* __restrict__ out5,
                                              float* __restrict__ out6,
                                              const float* __restrict__ invr,
                                              const float* __restrict__ invc) {
  __shared__ float ldsT[192 * 49];
  const int n = blockIdx.z, h = blockIdx.y, sb = blockIdx.x;
  const int S0 = sb * 192;
  const int t = threadIdx.x;
  const int sg = S0 + t;
  const float icv = invc[n * HW + sg];
  const float* invr_n = invr + n * HW;
  float* e_base = out1 + (size_t)n * SZ_QS;
  const int Q0 = h * 192;
  float acc[12];
#pragma unroll
  for (int i = 0; i < 12; ++i) acc[i] = 0.f;
  for (int ph = 0; ph < 4; ++ph) {
    const int qf0 = Q0 + ph * 48;
#pragma unroll
    for (int wi = 0; wi < 12; ++wi) {
#pragma unroll
      for (int pw = 0; pw < 4; ++pw) {
        const int col = wi * 4 + pw;
        const int q = qf0 + col;
        const size_t eoff = (size_t)q * HW + sg;
        const float e = e_base[eoff];
        const float pi = e * icv;
        e_base[eoff] = pi;
        out5[((size_t)((n * 144 + h * 12 + wi) * 16 + (ph * 4 + pw))) * HW + sg] = pi;
        acc[wi] += pi;
        ldsT[t * 49 + col] = e * invr_n[q];
      }
    }
    __syncthreads();
    const int u = t & 3, sB = t >> 2;
#pragma unroll
    for (int pass = 0; pass < 4; ++pass) {
      const int sl = pass * 48 + sB;
      const int sgl = S0 + sl;
      const int rs_ = sgl / 48, cs = sgl % 48;
      const int sp = (rs_ >> 2) * 12 + (cs >> 2);
      const int spp = (rs_ & 3) * 4 + (cs & 3);
      const size_t o2row = ((size_t)n * HW + sgl) * HW + qf0;
      const size_t o6row = (((size_t)n * 144 + sp) * 16 + spp) * HW + qf0;
#pragma unroll
      for (int k = 0; k < 3; ++k) {
        const int slot = u + k * 4;
        float4 v;
        v.x = ldsT[sl * 49 + slot * 4 + 0];
        v.y = ldsT[sl * 49 + slot * 4 + 1];
        v.z = ldsT[sl * 49 + slot * 4 + 2];
        v.w = ldsT[sl * 49 + slot * 4 + 3];
        *(float4*)(out2 + o2row + slot * 4) = v;
        *(float4*)(out6 + o6row + slot * 4) = v;
      }
    }
    __syncthreads();
  }
#pragma unroll
  for (int wi = 0; wi < 12; ++wi)
    out3[((size_t)(n * 144 + h * 12 + wi)) * HW + sg] = fminf(acc[wi], EPSC);
}

__global__ __launch_bounds__(256) void k_qd(const float* __restrict__ out6,
                                            float* __restrict__ out4) {
  const int n = blockIdx.y, sp = blockIdx.x;
  const float* b6 = out6 + (((size_t)n * 144 + sp) * 16) * HW;
  float* b4 = out4 + ((size_t)n * 144 + sp) * HW;
  for (int i = 0; i < 9; ++i) {
    const int qq = i * 256 + threadIdx.x;
    float s = 0.f;
#pragma unroll
    for (int spp = 0; spp < 16; ++spp) s += b6[(size_t)spp * HW + qq];
    b4[qq] = fminf(s, EPSC);
  }
}

// ---------------------------------------------------------------------------
extern "C" void kernel_launch(void* const* d_in, const int* in_sizes, int n_in,
                              void* d_out, int out_size, void* d_ws, size_t ws_size,
                              hipStream_t stream) {
  const float* mask_f = (const float*)d_in[0];
  const float* query_f = (const float*)d_in[1];
  float* out = (float*)d_out;
  float* out1 = out + O1;
  float* out2 = out + O2;
  float* out3 = out + O3;
  float* out4 = out + O4;
  float* out5 = out + O5;
  float* out6 = out + O6;

  const size_t abytes = (size_t)N_B * HW * CH * 2;  // 9,437,184 per operand
  const size_t sbytes = (size_t)N_B * HW * 4;       // 73,728 per sum array
  const size_t need = 2 * abytes + 4 * sbytes;

  if (ws_size >= need) {
    char* base = (char*)d_ws;
    __hip_bfloat16* Abf = (__hip_bfloat16*)base;
    __hip_bfloat16* Bbf = (__hip_bfloat16*)(base + abytes);
    float* sums = (float*)(base + 2 * abytes);
    float* rowsum = sums;
    float* colsum = sums + N_B * HW;

    k_tr<<<dim3(36, 4, 16), 256, 0, stream>>>(query_f, mask_f, Abf, Bbf, sums);
    k_p1<<<dim3(12, 12, 8), 512, 0, stream>>>(
        (const unsigned short*)Abf, (const unsigned short*)Bbf, rowsum, colsum);
    k_p2<<<dim3(12, 12, 8), 512, 0, stream>>>(
        (const unsigned short*)Abf, (const unsigned short*)Bbf,
        out1, out2, out3, out4, out5, out6, rowsum, colsum);
  } else {
    // Fallback: scratch carved from out regions; old validated 3-kernel path.
    __hip_bfloat16* Abf = (__hip_bfloat16*)out4;
    __hip_bfloat16* Bbf = (__hip_bfloat16*)out3;
    float* sums = (float*)((char*)out4 + abytes);
    float* invs = sums + 2 * (N_B * HW);
    float* rowsum = sums;
    float* colsum = sums + N_B * HW;
    float* invr = invs;
    float* invc = invs + N_B * HW;

    k_tr<<<dim3(36, 4, 16), 256, 0, stream>>>(query_f, mask_f, Abf, Bbf, nullptr);
    k_zero<<<dim3(36), 256, 0, stream>>>(sums);
    k_gemm_old<<<dim3(18, 18, 8), 256, 0, stream>>>(
        (const unsigned short*)Abf, (const unsigned short*)Bbf, out1, rowsum, colsum);
    k_inv<<<dim3(144), 256, 0, stream>>>(sums, invs, 1.0f);
    k_main<<<dim3(12, 12, 8), 192, 0, stream>>>(out1, out2, out3, out5, out6, invr, invc);
    k_qd<<<dim3(144, 8), 256, 0, stream>>>(out6, out4);
  }
}

// Round 13
// 215.897 us; speedup vs baseline: 1.0417x; 1.0417x over previous
//
#include <hip/hip_runtime.h>
#include <hip/hip_bf16.h>

#define N_B 8
#define CH 256
#define HW 2304           // 48*48
#define SZ_QS (2304LL*2304LL)
#define SCALE 0.0390625f  // 10/256
#define EPSC 0.999999f

typedef __attribute__((ext_vector_type(8))) short bf8_t;
typedef __attribute__((ext_vector_type(8))) unsigned short u16x8;
typedef __attribute__((ext_vector_type(4))) float f32x4;

// output offsets in floats
#define O1 0LL
#define O2 42467328LL
#define O3 84934656LL
#define O4 87588864LL
#define O5 90243072LL
#define O6 132710400LL

// async global->LDS, 16B per lane, linear LDS dest (wave-uniform base + lane*16)
__device__ __forceinline__ void gl_lds16(const unsigned short* g, unsigned short* l) {
  __builtin_amdgcn_global_load_lds(
      (const __attribute__((address_space(1))) unsigned int*)g,
      (__attribute__((address_space(3))) unsigned int*)l, 16, 0, 0);
}

// non-temporal 16B store (nt flag: bypass/minimize L2 pollution for
// write-once output streams)
__device__ __forceinline__ void nt_store4(float* p, f32x4 v) {
  __builtin_nontemporal_store(v, (f32x4*)p);
}

// ---------------------------------------------------------------------------
// Shared GEMM core: 192x192 tile, 512 thr (2x4 waves), K=256, BK=32
// double-buffered 2-phase pipeline (R11-proven).  smem = 48 KB staging.
// Produces exact f32 acc[6][3] (e = exp(SCALE*sim)) in C/D fragment layout.
// ---------------------------------------------------------------------------
__device__ __forceinline__ void gemm192(
    const unsigned short* __restrict__ Abf, const unsigned short* __restrict__ Bbf,
    unsigned short* __restrict__ smem, const int n, const int S0, const int Q0,
    const int t, f32x4 (&acc)[6][3]) {
  const int l = t & 63, w = t >> 6;
  const int wm = w >> 2, wn = w & 3;
  const int g = l >> 4, c = l & 15;

#pragma unroll
  for (int mi = 0; mi < 6; ++mi)
#pragma unroll
    for (int ni = 0; ni < 3; ++ni) {
      f32x4 z = {0.f, 0.f, 0.f, 0.f};
      acc[mi][ni] = z;
    }

  // staging: 24 chunks of 16 rows (12 A + 12 B), 3 per wave; source-swizzled.
  const int rrel = l >> 2;
  const int sseg = (l & 3) ^ ((l >> 3) & 3);
  const unsigned short* gAb = Abf + ((size_t)n * HW + Q0) * CH;
  const unsigned short* gBb = Bbf + ((size_t)n * HW + S0) * CH;
  const int ch0 = w * 3;

#define STAGE_CHUNK(chv, buf, k0)                                              \
  {                                                                            \
    const int isA = (chv) < 12;                                                \
    const int crel = isA ? (chv) : (chv)-12;                                   \
    const unsigned short* sp_ =                                                \
        (isA ? gAb : gBb) + (size_t)(crel * 16 + rrel) * CH + (k0) + sseg * 8; \
    unsigned short* dp_ = smem + (buf)*12288 + (isA ? 0 : 6144) + crel * 512;  \
    gl_lds16(sp_, dp_);                                                        \
  }

  STAGE_CHUNK(ch0 + 0, 0, 0);
  STAGE_CHUNK(ch0 + 1, 0, 0);
  STAGE_CHUNK(ch0 + 2, 0, 0);
  __syncthreads();

  int cur = 0;
#pragma unroll 2
  for (int step = 0; step < 8; ++step) {
    if (step < 7) {
      const int k0_ = (step + 1) * 32;
      STAGE_CHUNK(ch0 + 0, cur ^ 1, k0_);
      STAGE_CHUNK(ch0 + 1, cur ^ 1, k0_);
      STAGE_CHUNK(ch0 + 2, cur ^ 1, k0_);
    }
    const unsigned short* lA = smem + cur * 12288;
    const unsigned short* lB = lA + 6144;
    bf8_t af[6], bf_[3];
    const int sg_ = g ^ ((c >> 1) & 3);
#pragma unroll
    for (int mi = 0; mi < 6; ++mi) {
      const int r = wm * 96 + mi * 16 + c;
      af[mi] = *(const bf8_t*)(lA + r * 32 + sg_ * 8);
    }
#pragma unroll
    for (int ni = 0; ni < 3; ++ni) {
      const int r = wn * 48 + ni * 16 + c;
      bf_[ni] = *(const bf8_t*)(lB + r * 32 + sg_ * 8);
    }
#pragma unroll
    for (int mi = 0; mi < 6; ++mi)
#pragma unroll
      for (int ni = 0; ni < 3; ++ni)
        acc[mi][ni] = __builtin_amdgcn_mfma_f32_16x16x32_bf16(af[mi], bf_[ni], acc[mi][ni], 0, 0, 0);
    __syncthreads();  // drains stage loads + protects buffer swap
    cur ^= 1;
  }
#undef STAGE_CHUNK

#pragma unroll
  for (int mi = 0; mi < 6; ++mi)
#pragma unroll
    for (int ni = 0; ni < 3; ++ni)
#pragma unroll
      for (int r = 0; r < 4; ++r)
        acc[mi][ni][r] = __expf(acc[mi][ni][r] * SCALE);
}

// ---------------------------------------------------------------------------
// K0: transpose+convert fp32 [n][c][hw] -> bf16 [n][hw][c], wide 16B stores.
// NT loads on the fp32 input (never re-read — keep L2 for the bf16 panels).
// Side job: 36 blocks (y==0, z==0) zero the sum buffers (if zbuf != null).
// ---------------------------------------------------------------------------
__global__ __launch_bounds__(256) void k_tr(const float* __restrict__ q_in,
                                            const float* __restrict__ m_in,
                                            __hip_bfloat16* __restrict__ Abf,
                                            __hip_bfloat16* __restrict__ Bbf,
                                            float* __restrict__ zbuf) {
  __shared__ float lds[64][65];
  const int n = blockIdx.z >> 1, which = blockIdx.z & 1;
  const float* src = which ? m_in : q_in;
  __hip_bfloat16* dst = which ? Bbf : Abf;
  const int q0 = blockIdx.x * 64, c0 = blockIdx.y * 64;
  const int t = threadIdx.x;

  if (zbuf && blockIdx.y == 0 && blockIdx.z == 0) {
    const int i = (blockIdx.x * 256 + t) * 4;  // 36*256*4 = 36864 = 2*N_B*HW
    *(float4*)(zbuf + i) = make_float4(0.f, 0.f, 0.f, 0.f);
  }

  const int cl4 = t >> 4, q4 = (t & 15) * 4;
#pragma unroll
  for (int p = 0; p < 4; ++p) {
    const int cl = p * 16 + cl4;
    const f32x4 v = __builtin_nontemporal_load(
        (const f32x4*)(src + ((size_t)n * CH + c0 + cl) * HW + q0 + q4));
    lds[cl][q4 + 0] = v[0];
    lds[cl][q4 + 1] = v[1];
    lds[cl][q4 + 2] = v[2];
    lds[cl][q4 + 3] = v[3];
  }
  __syncthreads();

  const int c8 = (t & 7) * 8;
#pragma unroll
  for (int p = 0; p < 2; ++p) {
    const int ql = p * 32 + (t >> 3);
    u16x8 o;
#pragma unroll
    for (int k = 0; k < 8; ++k) {
      const __hip_bfloat16 h = __float2bfloat16(lds[c8 + k][ql]);
      o[k] = *(const unsigned short*)&h;
    }
    *(u16x8*)((unsigned short*)dst + ((size_t)n * HW + q0 + ql) * CH + c0 + c8) = o;
  }
}

__global__ __launch_bounds__(256) void k_zero(float* __restrict__ p) {
  const int i = (blockIdx.x * 256 + threadIdx.x) * 4;
  *(float4*)(p + i) = make_float4(0.f, 0.f, 0.f, 0.f);
}

__global__ __launch_bounds__(256) void k_inv(const float* __restrict__ s,
                                             float* __restrict__ inv,
                                             const float scale) {
  const int i = blockIdx.x * 256 + threadIdx.x;
  inv[i] = scale / s[i];
}

// ---------------------------------------------------------------------------
// Pass 1: pipelined GEMM + row/col sum atomics ONLY (no e materialization).
// ---------------------------------------------------------------------------
__global__ __launch_bounds__(512) void k_p1(
    const unsigned short* __restrict__ Abf, const unsigned short* __restrict__ Bbf,
    float* __restrict__ rowsum, float* __restrict__ colsum) {
  __shared__ char smem[49152];
  const int n = blockIdx.z;
  const int S0 = blockIdx.x * 192, Q0 = blockIdx.y * 192;
  const int t = threadIdx.x, l = t & 63, w = t >> 6;
  const int wm = w >> 2, wn = w & 3;
  const int g = l >> 4, c = l & 15;

  f32x4 acc[6][3];
  gemm192(Abf, Bbf, (unsigned short*)smem, n, S0, Q0, t, acc);

#pragma unroll
  for (int mi = 0; mi < 6; ++mi)
#pragma unroll
    for (int r = 0; r < 4; ++r) {
      float v = acc[mi][0][r] + acc[mi][1][r] + acc[mi][2][r];
      v += __shfl_xor(v, 1, 64);
      v += __shfl_xor(v, 2, 64);
      v += __shfl_xor(v, 4, 64);
      v += __shfl_xor(v, 8, 64);
      if (c == 0) atomicAdd(&rowsum[n * HW + Q0 + wm * 96 + mi * 16 + g * 4 + r], v);
    }
#pragma unroll
  for (int ni = 0; ni < 3; ++ni) {
    float v = 0.f;
#pragma unroll
    for (int mi = 0; mi < 6; ++mi)
#pragma unroll
      for (int r = 0; r < 4; ++r) v += acc[mi][ni][r];
    v += __shfl_xor(v, 16, 64);
    v += __shfl_xor(v, 32, 64);
    if (g == 0) atomicAdd(&colsum[n * HW + S0 + wn * 48 + ni * 16 + c], v);
  }
}

// ---------------------------------------------------------------------------
// Pass 2: recompute e via the same pipelined GEMM (exact f32), inverses
// inline, then epilogue phases A-D with NON-TEMPORAL stores on all outputs
// (write-once streams — keep L2 for the A/B staging panels).
// ---------------------------------------------------------------------------
__global__ __launch_bounds__(512) void k_p2(
    const unsigned short* __restrict__ Abf, const unsigned short* __restrict__ Bbf,
    float* __restrict__ out1, float* __restrict__ out2, float* __restrict__ out3,
    float* __restrict__ out4, float* __restrict__ out5, float* __restrict__ out6,
    const float* __restrict__ rowsum, const float* __restrict__ colsum) {
  __shared__ char smem[49152];
  const int n = blockIdx.z;
  const int bx = blockIdx.x, hq = blockIdx.y;
  const int S0 = bx * 192, Q0 = hq * 192;
  const int t = threadIdx.x, l = t & 63, w = t >> 6;
  const int wm = w >> 2, wn = w & 3;
  const int g = l >> 4, c = l & 15;

  f32x4 acc[6][3];
  gemm192(Abf, Bbf, (unsigned short*)smem, n, S0, Q0, t, acc);
  // last gemm barrier guarantees all LDS reads done -> safe to reuse as fb
  float* fb = (float*)smem;  // 48 x 196 floats

  // inverses (exact f32 sums)
  float icv[3];
#pragma unroll
  for (int ni = 0; ni < 3; ++ni)
    icv[ni] = 1.0f / colsum[n * HW + S0 + wn * 48 + ni * 16 + c];
  f32x4 irv6[6];
#pragma unroll
  for (int mi = 0; mi < 6; ++mi) {
    const int qloc = wm * 96 + mi * 16 + g * 4;
    const f32x4 rs = *(const f32x4*)(rowsum + n * HW + Q0 + qloc);
#pragma unroll
    for (int r = 0; r < 4; ++r) irv6[mi][r] = 1.0f / rs[r];
  }

  // Phase A: pi tile (out1 rows q, out5 remapped), 4 chunks of 48 q-rows
#pragma unroll
  for (int ch = 0; ch < 4; ++ch) {
    if (wm == (ch >> 1)) {
#pragma unroll
      for (int m3 = 0; m3 < 3; ++m3) {
        const int mi = (ch & 1) * 3 + m3;
        const int rowb = m3 * 16 + g * 4;
#pragma unroll
        for (int ni = 0; ni < 3; ++ni) {
          const int colb = wn * 48 + ni * 16 + c;
#pragma unroll
          for (int r = 0; r < 4; ++r)
            fb[(rowb + r) * 196 + colb] = acc[mi][ni][r] * icv[ni];
        }
      }
    }
    __syncthreads();
#pragma unroll
    for (int j = 0; j < 5; ++j) {
      const int idx = t + j * 512;
      if (idx < 2304) {
        const int row = idx / 48, col4 = idx % 48;
        const f32x4 v = *(const f32x4*)(fb + row * 196 + col4 * 4);
        nt_store4(out1 + ((size_t)n * HW + Q0 + ch * 48 + row) * HW + S0 + col4 * 4, v);
        const size_t r5 = ((size_t)n * 144 + hq * 12 + (row >> 2)) * 16 + ch * 4 + (row & 3);
        nt_store4(out5 + r5 * HW + S0 + col4 * 4, v);
      }
    }
    __syncthreads();
  }

  // Phase B: pq tile (out2 rows s, out6 remapped), 4 chunks of 48 s-rows (= wn)
#pragma unroll
  for (int ch = 0; ch < 4; ++ch) {
    if (wn == ch) {
#pragma unroll
      for (int mi = 0; mi < 6; ++mi) {
        const int colf = wm * 96 + mi * 16 + g * 4;
#pragma unroll
        for (int ni = 0; ni < 3; ++ni) {
          const f32x4 pq = acc[mi][ni] * irv6[mi];
          *(f32x4*)(fb + (ni * 16 + c) * 196 + colf) = pq;
        }
      }
    }
    __syncthreads();
#pragma unroll
    for (int j = 0; j < 5; ++j) {
      const int idx = t + j * 512;
      if (idx < 2304) {
        const int row = idx / 48, col4 = idx % 48;
        const f32x4 v = *(const f32x4*)(fb + row * 196 + col4 * 4);
        nt_store4(out2 + ((size_t)n * HW + S0 + ch * 48 + row) * HW + Q0 + col4 * 4, v);
        const size_t r6 = ((size_t)n * 144 + bx * 12 + (row >> 2)) * 16 + ch * 4 + (row & 3);
        nt_store4(out6 + r6 * HW + Q0 + col4 * 4, v);
      }
    }
    __syncthreads();
  }

  // Phase C: out3 (instance_d) — per-thread patch partials, combine wm halves
#pragma unroll
  for (int m3 = 0; m3 < 3; ++m3) {
    const int b = m3 * 4 + g;  // q-patch col 0..11
#pragma unroll
    for (int ni = 0; ni < 3; ++ni) {
      const int sl = wn * 48 + ni * 16 + c;
      float p = 0.f;
#pragma unroll
      for (int r = 0; r < 4; ++r) p += acc[m3][ni][r] + acc[m3 + 3][ni][r];
      fb[(wm * 12 + b) * 196 + sl] = p * icv[ni];
    }
  }
  __syncthreads();
#pragma unroll
  for (int j = 0; j < 5; ++j) {
    const int idx = t + j * 512;
    if (idx < 2304) {
      const int b = idx / 192, sl = idx % 192;
      const float v = fb[b * 196 + sl] + fb[(12 + b) * 196 + sl];
      __builtin_nontemporal_store(
          fminf(v, EPSC), out3 + ((size_t)n * 144 + hq * 12 + b) * HW + S0 + sl);
    }
  }
  __syncthreads();

  // Phase D: out4 (query_d) — 4-lane shfl, combine 4 wn waves in LDS
#pragma unroll
  for (int mi = 0; mi < 6; ++mi) {
    const int qloc = wm * 96 + mi * 16 + g * 4;
#pragma unroll
    for (int ni = 0; ni < 3; ++ni) {
      f32x4 pq = acc[mi][ni] * irv6[mi];
#pragma unroll
      for (int r = 0; r < 4; ++r) {
        pq[r] += __shfl_xor(pq[r], 1, 64);
        pq[r] += __shfl_xor(pq[r], 2, 64);
      }
      if ((c & 3) == 0) {
        const int pc = ni * 4 + (c >> 2);  // s-patch col 0..11
        *(f32x4*)(fb + (wn * 12 + pc) * 196 + qloc) = pq;
      }
    }
  }
  __syncthreads();
#pragma unroll
  for (int j = 0; j < 5; ++j) {
    const int idx = t + j * 512;
    if (idx < 2304) {
      const int pc = idx / 192, q = idx % 192;
      const float v = fb[pc * 196 + q] + fb[(12 + pc) * 196 + q] +
                      fb[(24 + pc) * 196 + q] + fb[(36 + pc) * 196 + q];
      __builtin_nontemporal_store(
          fminf(v, EPSC), out4 + ((size_t)n * 144 + bx * 12 + pc) * HW + Q0 + q);
    }
  }
}

// ===========================================================================
// Fallback path (ws too small): old validated kernels
// ===========================================================================
__global__ __launch_bounds__(256) void k_gemm_old(const unsigned short* __restrict__ Abf,
                                                  const unsigned short* __restrict__ Bbf,
                                                  float* __restrict__ out1,
                                                  float* __restrict__ rowsum,
                                                  float* __restrict__ colsum) {
  __shared__ unsigned short lA[128 * 64];
  __shared__ unsigned short lB[128 * 64];
  const int n = blockIdx.z;
  const int s0 = blockIdx.x * 128, q0 = blockIdx.y * 128;
  const int t = threadIdx.x, l = t & 63, w = t >> 6;
  const int wm = w >> 1, wn = w & 1;
  f32x4 acc[4][4];
#pragma unroll
  for (int mi = 0; mi < 4; ++mi)
#pragma unroll
    for (int ni = 0; ni < 4; ++ni) {
      f32x4 z = {0.f, 0.f, 0.f, 0.f};
      acc[mi][ni] = z;
    }
  const size_t baseA = ((size_t)n * HW + q0) * CH;
  const size_t baseB = ((size_t)n * HW + s0) * CH;
  const int jj = t & 7, rr = t >> 3;
  for (int kc = 0; kc < 4; ++kc) {
    const int k0 = kc * 64;
#pragma unroll
    for (int i = 0; i < 4; ++i) {
      const int r = i * 32 + rr;
      bf8_t va = *(const bf8_t*)(Abf + baseA + (size_t)r * CH + k0 + jj * 8);
      bf8_t vb = *(const bf8_t*)(Bbf + baseB + (size_t)r * CH + k0 + jj * 8);
      *(bf8_t*)(lA + r * 64 + ((jj ^ (r & 7)) * 8)) = va;
      *(bf8_t*)(lB + r * 64 + ((jj ^ (r & 7)) * 8)) = vb;
    }
    __syncthreads();
#pragma unroll
    for (int ks = 0; ks < 2; ++ks) {
      const int kb = ks * 4 + (l >> 4);
      bf8_t af[4], bfr[4];
#pragma unroll
      for (int mi = 0; mi < 4; ++mi) {
        const int r = wm * 64 + mi * 16 + (l & 15);
        af[mi] = *(const bf8_t*)(lA + r * 64 + ((kb ^ (r & 7)) * 8));
      }
#pragma unroll
      for (int ni = 0; ni < 4; ++ni) {
        const int r = wn * 64 + ni * 16 + (l & 15);
        bfr[ni] = *(const bf8_t*)(lB + r * 64 + ((kb ^ (r & 7)) * 8));
      }
#pragma unroll
      for (int mi = 0; mi < 4; ++mi)
#pragma unroll
        for (int ni = 0; ni < 4; ++ni)
          acc[mi][ni] = __builtin_amdgcn_mfma_f32_16x16x32_bf16(af[mi], bfr[ni], acc[mi][ni], 0, 0, 0);
    }
    __syncthreads();
  }
  float rp[4][4], cp[4];
#pragma unroll
  for (int mi = 0; mi < 4; ++mi)
#pragma unroll
    for (int r = 0; r < 4; ++r) rp[mi][r] = 0.f;
#pragma unroll
  for (int ni = 0; ni < 4; ++ni) cp[ni] = 0.f;
#pragma unroll
  for (int mi = 0; mi < 4; ++mi) {
    const int row = q0 + wm * 64 + mi * 16 + (l >> 4) * 4;
#pragma unroll
    for (int ni = 0; ni < 4; ++ni) {
      const int col = s0 + wn * 64 + ni * 16 + (l & 15);
      const size_t ob = ((size_t)n * HW + row) * HW + col;
#pragma unroll
      for (int r = 0; r < 4; ++r) {
        const float e = __expf(acc[mi][ni][r] * SCALE);
        out1[ob + (size_t)r * HW] = e;
        rp[mi][r] += e;
        cp[ni] += e;
      }
    }
  }
#pragma unroll
  for (int mi = 0; mi < 4; ++mi)
#pragma unroll
    for (int r = 0; r < 4; ++r) {
      float v = rp[mi][r];
      v += __shfl_xor(v, 1, 64);
      v += __shfl_xor(v, 2, 64);
      v += __shfl_xor(v, 4, 64);
      v += __shfl_xor(v, 8, 64);
      if ((l & 15) == 0)
        atomicAdd(&rowsum[n * HW + q0 + wm * 64 + mi * 16 + (l >> 4) * 4 + r], v);
    }
#pragma unroll
  for (int ni = 0; ni < 4; ++ni) {
    float v = cp[ni];
    v += __shfl_xor(v, 16, 64);
    v += __shfl_xor(v, 32, 64);
    if (l < 16) atomicAdd(&colsum[n * HW + s0 + wn * 64 + ni * 16 + l], v);
  }
}

__global__ __launch_bounds__(192) void k_main(float* __restrict__ out1,
                                              float* __restrict__ out2,
                                              float* __restrict__ out3,
                                              float* __restrict__ out5,
                                              float* __restrict__ out6,
                                              const float* __restrict__ invr,
                                              const float* __restrict__ invc) {
  __shared__ float ldsT[192 * 49];
  const int n = blockIdx.z, h = blockIdx.y, sb = blockIdx.x;
  const int S0 = sb * 192;
  const int t = threadIdx.x;
  const int sg = S0 + t;
  const float icv = invc[n * HW + sg];
  const float* invr_n = invr + n * HW;
  float* e_base = out1 + (size_t)n * SZ_QS;
  const int Q0 = h * 192;
  float acc[12];
#pragma unroll
  for (int i = 0; i < 12; ++i) acc[i] = 0.f;
  for (int ph = 0; ph < 4; ++ph) {
    const int qf0 = Q0 + ph * 48;
#pragma unroll
    for (int wi = 0; wi < 12; ++wi) {
#pragma unroll
      for (int pw = 0; pw < 4; ++pw) {
        const int col = wi * 4 + pw;
        const int q = qf0 + col;
        const size_t eoff = (size_t)q * HW + sg;
        const float e = e_base[eoff];
        const float pi = e * icv;
        e_base[eoff] = pi;
        out5[((size_t)((n * 144 + h * 12 + wi) * 16 + (ph * 4 + pw))) * HW + sg] = pi;
        acc[wi] += pi;
        ldsT[t * 49 + col] = e * invr_n[q];
      }
    }
    __syncthreads();
    const int u = t & 3, sB = t >> 2;
#pragma unroll
    for (int pass = 0; pass < 4; ++pass) {
      const int sl = pass * 48 + sB;
      const int sgl = S0 + sl;
      const int rs_ = sgl / 48, cs = sgl % 48;
      const int sp = (rs_ >> 2) * 12 + (cs >> 2);
      const int spp = (rs_ & 3) * 4 + (cs & 3);
      const size_t o2row = ((size_t)n * HW + sgl) * HW + qf0;
      const size_t o6row = (((size_t)n * 144 + sp) * 16 + spp) * HW + qf0;
#pragma unroll
      for (int k = 0; k < 3; ++k) {
        const int slot = u + k * 4;
        float4 v;
        v.x = ldsT[sl * 49 + slot * 4 + 0];
        v.y = ldsT[sl * 49 + slot * 4 + 1];
        v.z = ldsT[sl * 49 + slot * 4 + 2];
        v.w = ldsT[sl * 49 + slot * 4 + 3];
        *(float4*)(out2 + o2row + slot * 4) = v;
        *(float4*)(out6 + o6row + slot * 4) = v;
      }
    }
    __syncthreads();
  }
#pragma unroll
  for (int wi = 0; wi < 12; ++wi)
    out3[((size_t)(n * 144 + h * 12 + wi)) * HW + sg] = fminf(acc[wi], EPSC);
}

__global__ __launch_bounds__(256) void k_qd(const float* __restrict__ out6,
                                            float* __restrict__ out4) {
  const int n = blockIdx.y, sp = blockIdx.x;
  const float* b6 = out6 + (((size_t)n * 144 + sp) * 16) * HW;
  float* b4 = out4 + ((size_t)n * 144 + sp) * HW;
  for (int i = 0; i < 9; ++i) {
    const int qq = i * 256 + threadIdx.x;
    float s = 0.f;
#pragma unroll
    for (int spp = 0; spp < 16; ++spp) s += b6[(size_t)spp * HW + qq];
    b4[qq] = fminf(s, EPSC);
  }
}

// ---------------------------------------------------------------------------
extern "C" void kernel_launch(void* const* d_in, const int* in_sizes, int n_in,
                              void* d_out, int out_size, void* d_ws, size_t ws_size,
                              hipStream_t stream) {
  const float* mask_f = (const float*)d_in[0];
  const float* query_f = (const float*)d_in[1];
  float* out = (float*)d_out;
  float* out1 = out + O1;
  float* out2 = out + O2;
  float* out3 = out + O3;
  float* out4 = out + O4;
  float* out5 = out + O5;
  float* out6 = out + O6;

  const size_t abytes = (size_t)N_B * HW * CH * 2;  // 9,437,184 per operand
  const size_t sbytes = (size_t)N_B * HW * 4;       // 73,728 per sum array
  const size_t need = 2 * abytes + 4 * sbytes;

  if (ws_size >= need) {
    char* base = (char*)d_ws;
    __hip_bfloat16* Abf = (__hip_bfloat16*)base;
    __hip_bfloat16* Bbf = (__hip_bfloat16*)(base + abytes);
    float* sums = (float*)(base + 2 * abytes);
    float* rowsum = sums;
    float* colsum = sums + N_B * HW;

    k_tr<<<dim3(36, 4, 16), 256, 0, stream>>>(query_f, mask_f, Abf, Bbf, sums);
    k_p1<<<dim3(12, 12, 8), 512, 0, stream>>>(
        (const unsigned short*)Abf, (const unsigned short*)Bbf, rowsum, colsum);
    k_p2<<<dim3(12, 12, 8), 512, 0, stream>>>(
        (const unsigned short*)Abf, (const unsigned short*)Bbf,
        out1, out2, out3, out4, out5, out6, rowsum, colsum);
  } else {
    // Fallback: scratch carved from out regions; old validated 3-kernel path.
    __hip_bfloat16* Abf = (__hip_bfloat16*)out4;
    __hip_bfloat16* Bbf = (__hip_bfloat16*)out3;
    float* sums = (float*)((char*)out4 + abytes);
    float* invs = sums + 2 * (N_B * HW);
    float* rowsum = sums;
    float* colsum = sums + N_B * HW;
    float* invr = invs;
    float* invc = invs + N_B * HW;

    k_tr<<<dim3(36, 4, 16), 256, 0, stream>>>(query_f, mask_f, Abf, Bbf, nullptr);
    k_zero<<<dim3(36), 256, 0, stream>>>(sums);
    k_gemm_old<<<dim3(18, 18, 8), 256, 0, stream>>>(
        (const unsigned short*)Abf, (const unsigned short*)Bbf, out1, rowsum, colsum);
    k_inv<<<dim3(144), 256, 0, stream>>>(sums, invs, 1.0f);
    k_main<<<dim3(12, 12, 8), 192, 0, stream>>>(out1, out2, out3, out5, out6, invr, invc);
    k_qd<<<dim3(144, 8), 256, 0, stream>>>(out6, out4);
  }
}